// Round 7
// baseline (1439.822 us; speedup 1.0000x reference)
//
#include <hip/hip_runtime.h>
#include <hip/hip_fp16.h>
#include <math.h>

#define NN 50000
#define EE 800000
#define HIDDEN 128
#define NGRAPH 50
#define POOL_BLOCKS ((NN + 15) / 16)

struct __align__(8) kv8 { __half2 k2, v2; };

// ---------------- CSR build ----------------
__global__ void k_deg(const int* __restrict__ eidx, int* __restrict__ cnt) {
    int e = blockIdx.x * blockDim.x + threadIdx.x;
    if (e < EE) atomicAdd(&cnt[eidx[EE + e]], 1);
}

// scan + housekeeping: exclusive-scan deg->row_ptr, zero cnt (scatter cursor),
// zero bn_acc3 / gsum / gcnt
__global__ void k_scan(int* __restrict__ cnt, int* __restrict__ row_ptr,
                       float* __restrict__ bn_acc3, float* __restrict__ gsum,
                       int* __restrict__ gcnt) {
    __shared__ int wsum[16];
    __shared__ int carry_s;
    int t = threadIdx.x;
    int lane = t & 63, w = t >> 6;
    if (t < 768) bn_acc3[t] = 0.f;
    if (t < 64) { gsum[t] = 0.f; gcnt[t] = 0; }
    if (t == 0) carry_s = 0;
    __syncthreads();
    for (int base = 0; base < NN; base += 1024) {
        int i = base + t;
        int v = (i < NN) ? cnt[i] : 0;
        int s = v;
#pragma unroll
        for (int o = 1; o < 64; o <<= 1) {
            int u = __shfl_up(s, o);
            if (lane >= o) s += u;
        }
        if (lane == 63) wsum[w] = s;
        __syncthreads();
        if (w == 0) {
            int ws = (lane < 16) ? wsum[lane] : 0;
#pragma unroll
            for (int o = 1; o < 16; o <<= 1) {
                int u = __shfl_up(ws, o);
                if (lane >= o) ws += u;
            }
            if (lane < 16) wsum[lane] = ws;
        }
        __syncthreads();
        int wpre = (w == 0) ? 0 : wsum[w - 1];
        int carry = carry_s;
        if (i < NN) { row_ptr[i] = carry + wpre + s - v; cnt[i] = 0; }
        __syncthreads();
        if (t == 1023) carry_s = carry + wpre + s;
        __syncthreads();
    }
    if (t == 0) row_ptr[NN] = carry_s;
}

// scatter: build CSR-ordered src-index and edge-attr arrays
__global__ void k_scatter(const int* __restrict__ eidx, const float* __restrict__ eattr,
                          const int* __restrict__ row_ptr,
                          int* __restrict__ cur, int* __restrict__ esrc, float* __restrict__ eat2) {
    int e = blockIdx.x * blockDim.x + threadIdx.x;
    if (e < EE) {
        int d = eidx[EE + e];
        int s = eidx[e];
        int p = atomicAdd(&cur[d], 1);
        int pos = row_ptr[d] + p;
        esrc[pos] = s;
        float2 ea = *(const float2*)&eattr[2 * (size_t)e];
        *(float2*)&eat2[2 * (size_t)pos] = ea;
    }
}

// ---- fused 4-way GEMM: q,xr fp32; k,v packed fp16 interleaved.
// When use_ab: BN affine+ELU applied to input X, computed in-block from bn_acc stats.
__global__ __launch_bounds__(256) void k_gemm4(
    const float* __restrict__ X,
    const float* __restrict__ Wq, const float* __restrict__ bq,
    const float* __restrict__ Wk, const float* __restrict__ bk,
    const float* __restrict__ Wv, const float* __restrict__ bv,
    const float* __restrict__ Ws, const float* __restrict__ bs,
    const float* __restrict__ bn_acc, const float* __restrict__ gamma,
    const float* __restrict__ beta, int use_ab,
    float* __restrict__ qo, __half* __restrict__ kvh, float* __restrict__ xro)
{
    __shared__ float xs[64][132];
    __shared__ float ab_s[256];
    int t = threadIdx.x;
    int m0 = blockIdx.x * 64;
    if (use_ab) {
        if (t < 128) {
            float mu = bn_acc[t] * (1.f / NN);
            float var = bn_acc[128 + t] * (1.f / NN) - mu * mu;
            float inv = rsqrtf(var + 1e-5f);
            float a = inv * gamma[t];
            ab_s[t] = a;
            ab_s[128 + t] = beta[t] - mu * a;
        }
        __syncthreads();
    }
#pragma unroll
    for (int i = 0; i < 8; ++i) {
        int f = t + 256 * i;          // float4 index within 64x32
        int r = f >> 5, c4 = (f & 31) << 2;
        float4 val = make_float4(0.f, 0.f, 0.f, 0.f);
        if (m0 + r < NN) val = *(const float4*)&X[(size_t)(m0 + r) * 128 + c4];
        if (use_ab) {
            float4 a = *(const float4*)&ab_s[c4];
            float4 bb = *(const float4*)&ab_s[128 + c4];
            float z;
            z = fmaf(val.x, a.x, bb.x); val.x = z > 0.f ? z : expm1f(z);
            z = fmaf(val.y, a.y, bb.y); val.y = z > 0.f ? z : expm1f(z);
            z = fmaf(val.z, a.z, bb.z); val.z = z > 0.f ? z : expm1f(z);
            z = fmaf(val.w, a.w, bb.w); val.w = z > 0.f ? z : expm1f(z);
        }
        *(float4*)&xs[r][c4] = val;
    }
    __syncthreads();
    int cg = t & 15, ng = t >> 4;
    int c0 = cg * 8;
    int mb = ng * 4;
    const float* Wm[4] = {Wq, Wk, Wv, Ws};
    const float* bm[4] = {bq, bk, bv, bs};
    __half2 khold[4][4];
#pragma unroll
    for (int w = 0; w < 4; ++w) {
        const float* __restrict__ W = Wm[w];
        float acc[4][8];
#pragma unroll
        for (int i = 0; i < 4; i++)
#pragma unroll
            for (int j = 0; j < 8; j++) acc[i][j] = 0.f;
        for (int k = 0; k < 128; k += 4) {
            float4 xa[4];
#pragma unroll
            for (int i = 0; i < 4; i++) xa[i] = *(const float4*)&xs[mb + i][k];
            float4 wr[4][2];
#pragma unroll
            for (int kk = 0; kk < 4; kk++) {
                wr[kk][0] = *(const float4*)&W[(k + kk) * 128 + c0];
                wr[kk][1] = *(const float4*)&W[(k + kk) * 128 + c0 + 4];
            }
#pragma unroll
            for (int kk = 0; kk < 4; kk++) {
                float wv[8] = {wr[kk][0].x, wr[kk][0].y, wr[kk][0].z, wr[kk][0].w,
                               wr[kk][1].x, wr[kk][1].y, wr[kk][1].z, wr[kk][1].w};
#pragma unroll
                for (int i = 0; i < 4; i++) {
                    float xv = ((const float*)&xa[i])[kk];
#pragma unroll
                    for (int j = 0; j < 8; j++) acc[i][j] = fmaf(xv, wv[j], acc[i][j]);
                }
            }
        }
        float bb[8];
        *(float4*)&bb[0] = *(const float4*)&bm[w][c0];
        *(float4*)&bb[4] = *(const float4*)&bm[w][c0 + 4];
        if (w == 0 || w == 3) {
            float* om = (w == 0) ? qo : xro;
#pragma unroll
            for (int i = 0; i < 4; i++) {
                int node = m0 + mb + i;
                if (node < NN) {
                    float4 o0 = make_float4(acc[i][0] + bb[0], acc[i][1] + bb[1],
                                            acc[i][2] + bb[2], acc[i][3] + bb[3]);
                    float4 o1 = make_float4(acc[i][4] + bb[4], acc[i][5] + bb[5],
                                            acc[i][6] + bb[6], acc[i][7] + bb[7]);
                    *(float4*)&om[(size_t)node * 128 + c0] = o0;
                    *(float4*)&om[(size_t)node * 128 + c0 + 4] = o1;
                }
            }
        } else if (w == 1) {
#pragma unroll
            for (int i = 0; i < 4; i++)
#pragma unroll
                for (int j = 0; j < 4; j++)
                    khold[i][j] = __float22half2_rn(
                        make_float2(acc[i][2 * j] + bb[2 * j], acc[i][2 * j + 1] + bb[2 * j + 1]));
        } else {  // w == 2: interleaved {k0,k1,v0,v1} per channel pair
#pragma unroll
            for (int i = 0; i < 4; i++) {
                int node = m0 + mb + i;
                if (node < NN) {
#pragma unroll
                    for (int j = 0; j < 4; j++) {
                        kv8 p;
                        p.k2 = khold[i][j];
                        p.v2 = __float22half2_rn(
                            make_float2(acc[i][2 * j] + bb[2 * j], acc[i][2 * j + 1] + bb[2 * j + 1]));
                        *(kv8*)&kvh[(size_t)node * 256 + 2 * c0 + 4 * j] = p;
                    }
                }
            }
        }
    }
}

// ---------------- attention + gate + BN-stats (one wave per dst node) ----------------
// Masked groups of 8 with cross-group software pipeline (up to 16 gathers in flight).
// Edge-embedding decomposed into per-head scalars cx,cy,cb.
__global__ __launch_bounds__(256) void k_attn(
    const float* __restrict__ q, const __half* __restrict__ kvh,
    const float* __restrict__ xr,
    const int* __restrict__ esrc, const float* __restrict__ eat2,
    const int* __restrict__ row_ptr,
    const float* __restrict__ We, const float* __restrict__ be,
    const float* __restrict__ Wb,
    float* __restrict__ out2, float* __restrict__ bn_accum)
{
    int t = threadIdx.x;
    int lane = t & 63;
    int wid = t >> 6;
    int gwave = blockIdx.x * 4 + wid;
    int nwaves = gridDim.x * 4;
    int ch = lane * 2;
    size_t lane8 = 4 * lane;           // half offset within a node's 256-half kv row
    float2 we0 = *(const float2*)&We[ch];
    float2 we1 = *(const float2*)&We[128 + ch];
    float2 beL = *(const float2*)&be[ch];
    float2 wb_o = *(const float2*)&Wb[ch];
    float2 wb_r = *(const float2*)&Wb[128 + ch];
    float2 wb_d = *(const float2*)&Wb[256 + ch];
    const float eta = 0.17677669529663687f * 1.4426950408889634f;  // (1/sqrt(32))*log2(e)
    float bnsx = 0.f, bnsy = 0.f, bnqx = 0.f, bnqy = 0.f;

    for (int n = gwave; n < NN; n += nwaves) {
        int rs = __builtin_amdgcn_readfirstlane(row_ptr[n]);
        int re = __builtin_amdgcn_readfirstlane(row_ptr[n + 1]);
        float2 qv = *(const float2*)&q[(size_t)n * 128 + ch];
        float2 qs = make_float2(qv.x * eta, qv.y * eta);
        // per-head scalars for the edge-embedding contribution (reduce over 16 lanes)
        float cx = qs.x * we0.x + qs.y * we0.y;
        float cy = qs.x * we1.x + qs.y * we1.y;
        float cb_ = qs.x * beL.x + qs.y * beL.y;
#pragma unroll
        for (int o = 1; o < 16; o <<= 1) {
            cx += __shfl_xor(cx, o);
            cy += __shfl_xor(cy, o);
            cb_ += __shfl_xor(cb_, o);
        }
        float den = 0.f, Sx = 0.f, Sy = 0.f, ax = 0.f, ay = 0.f;

        for (int cbase = rs; cbase < re; cbase += 64) {
            int cnum = re - cbase; if (cnum > 64) cnum = 64;
            int mi = cbase + lane;
            int sv = 0;
            float2 av = make_float2(0.f, 0.f);
            if (mi < re) {
                sv = esrc[mi];
                av = *(const float2*)&eat2[2 * (size_t)mi];
            }
            kv8 cur[8], nxt[8];
#pragma unroll
            for (int j = 0; j < 8; j++) {
                int s = __shfl(sv, j);
                cur[j] = *(const kv8*)&kvh[(size_t)s * 256 + lane8];
            }
            for (int base = 0; base < cnum; base += 8) {
                int nb = base + 8;
                if (nb < cnum) {
#pragma unroll
                    for (int j = 0; j < 8; j++) {
                        int s = __shfl(sv, nb + j);
                        nxt[j] = *(const kv8*)&kvh[(size_t)s * 256 + lane8];
                    }
                }
                int m = cnum - base; if (m > 8) m = 8;
#pragma unroll
                for (int j = 0; j < 8; j++) {
                    float eax = __shfl(av.x, base + j);
                    float eay = __shfl(av.y, base + j);
                    float2 kf = __half22float2(cur[j].k2);
                    float2 vf = __half22float2(cur[j].v2);
                    float p = qs.x * kf.x + qs.y * kf.y;
                    p += __shfl_xor(p, 1);
                    p += __shfl_xor(p, 2);
                    p += __shfl_xor(p, 4);
                    p += __shfl_xor(p, 8);
                    float alpha = p + fmaf(cx, eax, fmaf(cy, eay, cb_));
                    alpha = (j < m) ? alpha : -1.0e30f;
                    float exv = exp2f(alpha);
                    den += exv;
                    Sx = fmaf(exv, eax, Sx);
                    Sy = fmaf(exv, eay, Sy);
                    ax = fmaf(exv, vf.x, ax);
                    ay = fmaf(exv, vf.y, ay);
                }
                if (nb < cnum) {
#pragma unroll
                    for (int j = 0; j < 8; j++) cur[j] = nxt[j];
                }
            }
        }
        float rden = 1.f / (den + 1e-16f);
        float axn = (ax + Sx * we0.x + Sy * we1.x + den * beL.x) * rden;
        float ayn = (ay + Sx * we0.y + Sy * we1.y + den * beL.y) * rden;
        // beta gate
        float2 xv = *(const float2*)&xr[(size_t)n * 128 + ch];
        float gp = axn * wb_o.x + ayn * wb_o.y + xv.x * wb_r.x + xv.y * wb_r.y
                 + (axn - xv.x) * wb_d.x + (ayn - xv.y) * wb_d.y;
        gp += __shfl_xor(gp, 1);
        gp += __shfl_xor(gp, 2);
        gp += __shfl_xor(gp, 4);
        gp += __shfl_xor(gp, 8);
        gp += __shfl_xor(gp, 16);
        gp += __shfl_xor(gp, 32);
        float gate = 1.f / (1.f + __expf(-gp));
        float ox = gate * xv.x + (1.f - gate) * axn;
        float oy = gate * xv.y + (1.f - gate) * ayn;
        *(float2*)&out2[(size_t)n * 128 + ch] = make_float2(ox, oy);
        bnsx += ox; bnsy += oy;
        bnqx = fmaf(ox, ox, bnqx); bnqy = fmaf(oy, oy, bnqy);
    }
    // block-level BN partial reduce
    __shared__ float s_sum[2][256], s_sq[2][256];
    s_sum[0][t] = bnsx; s_sum[1][t] = bnsy;
    s_sq[0][t] = bnqx;  s_sq[1][t] = bnqy;
    __syncthreads();
    if (t < 64) {
        float sx = s_sum[0][t] + s_sum[0][64 + t] + s_sum[0][128 + t] + s_sum[0][192 + t];
        float sy = s_sum[1][t] + s_sum[1][64 + t] + s_sum[1][128 + t] + s_sum[1][192 + t];
        float qx = s_sq[0][t] + s_sq[0][64 + t] + s_sq[0][128 + t] + s_sq[0][192 + t];
        float qy = s_sq[1][t] + s_sq[1][64 + t] + s_sq[1][128 + t] + s_sq[1][192 + t];
        int c = 2 * t;
        atomicAdd(&bn_accum[c], sx);
        atomicAdd(&bn_accum[c + 1], sy);
        atomicAdd(&bn_accum[128 + c], qx);
        atomicAdd(&bn_accum[128 + c + 1], qy);
    }
}

// ------- readout: BN affine+ELU+dot(Wout), LDS per-graph accumulate, one flush per block,
//         last block (ticket in gcnt[63]) writes the final output -------
__global__ __launch_bounds__(256) void k_pool(const float* __restrict__ x,
                                              const float* __restrict__ bn_acc,
                                              const float* __restrict__ gamma,
                                              const float* __restrict__ beta,
                                              const float* __restrict__ Wout,
                                              const int* __restrict__ batch,
                                              float* __restrict__ gsum, int* __restrict__ gcnt,
                                              const float* __restrict__ bout,
                                              const float* __restrict__ obias,
                                              float* __restrict__ out) {
    __shared__ float lsum[NGRAPH];
    __shared__ int lcnt[NGRAPH];
    __shared__ float ab_s[256];
    __shared__ int slast;
    int t = threadIdx.x;
    if (t < NGRAPH) { lsum[t] = 0.f; lcnt[t] = 0; }
    if (t < 128) {
        float mu = bn_acc[t] * (1.f / NN);
        float var = bn_acc[128 + t] * (1.f / NN) - mu * mu;
        float inv = rsqrtf(var + 1e-5f);
        float a = inv * gamma[t];
        ab_s[t] = a;
        ab_s[128 + t] = beta[t] - mu * a;
    }
    __syncthreads();
    int lane = t & 63;
    int wid = t >> 6;
    int ch = lane * 2;
    float2 wo = *(const float2*)&Wout[ch];
    float2 a = *(const float2*)&ab_s[ch];
    float2 b = *(const float2*)&ab_s[128 + ch];
    int base = blockIdx.x * 16 + wid * 4;
#pragma unroll
    for (int i = 0; i < 4; i++) {
        int n = base + i;
        if (n < NN) {
            float2 xv = *(const float2*)&x[(size_t)n * 128 + ch];
            float z0 = fmaf(xv.x, a.x, b.x); z0 = z0 > 0.f ? z0 : expm1f(z0);
            float z1 = fmaf(xv.y, a.y, b.y); z1 = z1 > 0.f ? z1 : expm1f(z1);
            float p = z0 * wo.x + z1 * wo.y;
            p += __shfl_xor(p, 1);
            p += __shfl_xor(p, 2);
            p += __shfl_xor(p, 4);
            p += __shfl_xor(p, 8);
            p += __shfl_xor(p, 16);
            p += __shfl_xor(p, 32);
            if (lane == 0) {
                int g = batch[n];
                atomicAdd(&lsum[g], p);
                atomicAdd(&lcnt[g], 1);
            }
        }
    }
    __syncthreads();
    if (t < NGRAPH && lcnt[t] > 0) {
        atomicAdd(&gsum[t], lsum[t]);
        atomicAdd(&gcnt[t], lcnt[t]);
    }
    __threadfence();
    __syncthreads();
    if (t == 0) {
        int old = atomicAdd(&gcnt[63], 1);
        slast = (old == POOL_BLOCKS - 1) ? 1 : 0;
    }
    __syncthreads();
    if (slast && t < NGRAPH) {
        float s = atomicAdd(&gsum[t], 0.f);     // device-scope read, bypasses stale L1
        int c = atomicAdd(&gcnt[t], 0);
        out[t] = s / fmaxf((float)c, 1.f) + bout[0] + obias[0];
    }
}

extern "C" void kernel_launch(void* const* d_in, const int* in_sizes, int n_in,
                              void* d_out, int out_size, void* d_ws, size_t ws_size,
                              hipStream_t stream) {
    const float* x_in       = (const float*)d_in[0];
    const int* eidx         = (const int*)d_in[1];
    const float* eattr      = (const float*)d_in[2];
    const int* batch        = (const int*)d_in[3];
    const float* Wq         = (const float*)d_in[4];
    const float* bq         = (const float*)d_in[5];
    const float* Wk         = (const float*)d_in[6];
    const float* bk         = (const float*)d_in[7];
    const float* Wv         = (const float*)d_in[8];
    const float* bv         = (const float*)d_in[9];
    const float* We         = (const float*)d_in[10];
    const float* be         = (const float*)d_in[11];
    const float* Wskip      = (const float*)d_in[12];
    const float* bskip      = (const float*)d_in[13];
    const float* Wbeta      = (const float*)d_in[14];
    const float* bn_gamma   = (const float*)d_in[15];
    const float* bn_beta    = (const float*)d_in[16];
    const float* Wout       = (const float*)d_in[17];
    const float* bout       = (const float*)d_in[18];
    const float* obias      = (const float*)d_in[19];
    float* out = (float*)d_out;

    char* ws = (char*)d_ws;
    size_t off = 0;
    auto alloc = [&](size_t bytes) -> void* {
        off = (off + 255) & ~(size_t)255;
        void* p = ws + off;
        off += bytes;
        return p;
    };
    const size_t NF = (size_t)NN * 128 * sizeof(float);
    float* xbuf    = (float*)alloc(NF);
    float* qb      = (float*)alloc(NF);
    float* xrb     = (float*)alloc(NF);
    __half* kvh    = (__half*)alloc((size_t)NN * 256 * sizeof(__half));
    int* row_ptr   = (int*)alloc((NN + 1) * sizeof(int));
    int* cnt       = (int*)alloc(NN * sizeof(int));
    int* esrc      = (int*)alloc(EE * sizeof(int));
    float* eat2    = (float*)alloc((size_t)EE * 2 * sizeof(float));
    float* bn_acc3 = (float*)alloc(3 * 256 * sizeof(float));
    float* gsum    = (float*)alloc(64 * sizeof(float));
    int* gcnt      = (int*)alloc(64 * sizeof(int));
    (void)ws_size; (void)n_in; (void)in_sizes; (void)out_size;

    // ---- CSR build (dst -> src, eattr reordered) + zero aux buffers ----
    hipMemsetAsync(cnt, 0, NN * sizeof(int), stream);
    k_deg<<<(EE + 255) / 256, 256, 0, stream>>>(eidx, cnt);
    k_scan<<<1, 1024, 0, stream>>>(cnt, row_ptr, bn_acc3, gsum, gcnt);
    k_scatter<<<(EE + 255) / 256, 256, 0, stream>>>(eidx, eattr, row_ptr, cnt, esrc, eat2);

    // ---- layers ----
    for (int l = 0; l < 3; ++l) {
        const float* Xl = (l == 0) ? x_in : xbuf;
        const float* prev_acc = (l == 0) ? bn_acc3 : bn_acc3 + (l - 1) * 256;
        k_gemm4<<<(NN + 63) / 64, 256, 0, stream>>>(
            Xl,
            Wq + (size_t)l * 16384, bq + l * 128,
            Wk + (size_t)l * 16384, bk + l * 128,
            Wv + (size_t)l * 16384, bv + l * 128,
            Wskip + (size_t)l * 16384, bskip + l * 128,
            prev_acc, bn_gamma + (l == 0 ? 0 : (l - 1) * 128),
            bn_beta + (l == 0 ? 0 : (l - 1) * 128), (l == 0) ? 0 : 1,
            qb, kvh, xrb);
        k_attn<<<3125, 256, 0, stream>>>(
            qb, kvh, xrb, esrc, eat2, row_ptr,
            We + (size_t)l * 256, be + l * 128, Wbeta + (size_t)l * 384,
            xbuf, bn_acc3 + l * 256);
    }

    // ---- readout (BN affine+ELU of layer-2 fused in; final write by last block) ----
    k_pool<<<POOL_BLOCKS, 256, 0, stream>>>(xbuf, bn_acc3 + 2 * 256,
                                            bn_gamma + 2 * 128, bn_beta + 2 * 128,
                                            Wout, batch, gsum, gcnt, bout, obias, out);
}

// Round 8
// 1283.446 us; speedup vs baseline: 1.1218x; 1.1218x over previous
//
#include <hip/hip_runtime.h>
#include <hip/hip_fp16.h>
#include <math.h>

#define NN 50000
#define EE 800000
#define HIDDEN 128
#define NGRAPH 50

struct __align__(8) kv8 { __half2 k2, v2; };

// ---------------- CSR build ----------------
__global__ void k_deg(const int* __restrict__ eidx, int* __restrict__ cnt) {
    int e = blockIdx.x * blockDim.x + threadIdx.x;
    if (e < EE) atomicAdd(&cnt[eidx[EE + e]], 1);
}

// scan + housekeeping: exclusive-scan deg->row_ptr (4 elems/thread), zero cnt,
// zero bn_acc3 / gsum / gcnt
__global__ void k_scan(int* __restrict__ cnt, int* __restrict__ row_ptr,
                       float* __restrict__ bn_acc3, float* __restrict__ gsum,
                       int* __restrict__ gcnt) {
    __shared__ int wsum[16];
    __shared__ int carry_s;
    int t = threadIdx.x;
    int lane = t & 63, w = t >> 6;
    if (t < 768) bn_acc3[t] = 0.f;
    if (t < 64) { gsum[t] = 0.f; gcnt[t] = 0; }
    if (t == 0) carry_s = 0;
    __syncthreads();
    for (int base = 0; base < NN; base += 4096) {
        int i0 = base + t * 4;
        int v[4];
#pragma unroll
        for (int j = 0; j < 4; j++) v[j] = (i0 + j < NN) ? cnt[i0 + j] : 0;
        int s4 = v[0] + v[1] + v[2] + v[3];
        int s = s4;
#pragma unroll
        for (int o = 1; o < 64; o <<= 1) {
            int u = __shfl_up(s, o);
            if (lane >= o) s += u;
        }
        if (lane == 63) wsum[w] = s;
        __syncthreads();
        if (w == 0) {
            int ws = (lane < 16) ? wsum[lane] : 0;
#pragma unroll
            for (int o = 1; o < 16; o <<= 1) {
                int u = __shfl_up(ws, o);
                if (lane >= o) ws += u;
            }
            if (lane < 16) wsum[lane] = ws;
        }
        __syncthreads();
        int wpre = (w == 0) ? 0 : wsum[w - 1];
        int run = carry_s + wpre + s - s4;      // exclusive start for this thread's 4
#pragma unroll
        for (int j = 0; j < 4; j++) {
            if (i0 + j < NN) { row_ptr[i0 + j] = run; cnt[i0 + j] = 0; run += v[j]; }
        }
        __syncthreads();
        if (t == 0) carry_s += wsum[15];
        __syncthreads();
    }
    if (t == 0) row_ptr[NN] = carry_s;
}

// scatter: build CSR-ordered src-index and edge-attr arrays
__global__ void k_scatter(const int* __restrict__ eidx, const float* __restrict__ eattr,
                          const int* __restrict__ row_ptr,
                          int* __restrict__ cur, int* __restrict__ esrc, float* __restrict__ eat2) {
    int e = blockIdx.x * blockDim.x + threadIdx.x;
    if (e < EE) {
        int d = eidx[EE + e];
        int s = eidx[e];
        int p = atomicAdd(&cur[d], 1);
        int pos = row_ptr[d] + p;
        esrc[pos] = s;
        float2 ea = *(const float2*)&eattr[2 * (size_t)e];
        *(float2*)&eat2[2 * (size_t)pos] = ea;
    }
}

// ---- fused 4-way GEMM: q,xr fp32; k,v packed fp16 interleaved.
// When use_ab: BN affine+ELU applied to input X, computed in-block from bn_acc stats.
__global__ __launch_bounds__(256) void k_gemm4(
    const float* __restrict__ X,
    const float* __restrict__ Wq, const float* __restrict__ bq,
    const float* __restrict__ Wk, const float* __restrict__ bk,
    const float* __restrict__ Wv, const float* __restrict__ bv,
    const float* __restrict__ Ws, const float* __restrict__ bs,
    const float* __restrict__ bn_acc, const float* __restrict__ gamma,
    const float* __restrict__ beta, int use_ab,
    float* __restrict__ qo, __half* __restrict__ kvh, float* __restrict__ xro)
{
    __shared__ float xs[64][132];
    __shared__ float ab_s[256];
    int t = threadIdx.x;
    int m0 = blockIdx.x * 64;
    if (use_ab) {
        if (t < 128) {
            float mu = bn_acc[t] * (1.f / NN);
            float var = bn_acc[128 + t] * (1.f / NN) - mu * mu;
            float inv = rsqrtf(var + 1e-5f);
            float a = inv * gamma[t];
            ab_s[t] = a;
            ab_s[128 + t] = beta[t] - mu * a;
        }
        __syncthreads();
    }
#pragma unroll
    for (int i = 0; i < 8; ++i) {
        int f = t + 256 * i;          // float4 index within 64x32
        int r = f >> 5, c4 = (f & 31) << 2;
        float4 val = make_float4(0.f, 0.f, 0.f, 0.f);
        if (m0 + r < NN) val = *(const float4*)&X[(size_t)(m0 + r) * 128 + c4];
        if (use_ab) {
            float4 a = *(const float4*)&ab_s[c4];
            float4 bb = *(const float4*)&ab_s[128 + c4];
            float z;
            z = fmaf(val.x, a.x, bb.x); val.x = z > 0.f ? z : expm1f(z);
            z = fmaf(val.y, a.y, bb.y); val.y = z > 0.f ? z : expm1f(z);
            z = fmaf(val.z, a.z, bb.z); val.z = z > 0.f ? z : expm1f(z);
            z = fmaf(val.w, a.w, bb.w); val.w = z > 0.f ? z : expm1f(z);
        }
        *(float4*)&xs[r][c4] = val;
    }
    __syncthreads();
    int cg = t & 15, ng = t >> 4;
    int c0 = cg * 8;
    int mb = ng * 4;
    const float* Wm[4] = {Wq, Wk, Wv, Ws};
    const float* bm[4] = {bq, bk, bv, bs};
    __half2 khold[4][4];
#pragma unroll
    for (int w = 0; w < 4; ++w) {
        const float* __restrict__ W = Wm[w];
        float acc[4][8];
#pragma unroll
        for (int i = 0; i < 4; i++)
#pragma unroll
            for (int j = 0; j < 8; j++) acc[i][j] = 0.f;
        for (int k = 0; k < 128; k += 4) {
            float4 xa[4];
#pragma unroll
            for (int i = 0; i < 4; i++) xa[i] = *(const float4*)&xs[mb + i][k];
            float4 wr[4][2];
#pragma unroll
            for (int kk = 0; kk < 4; kk++) {
                wr[kk][0] = *(const float4*)&W[(k + kk) * 128 + c0];
                wr[kk][1] = *(const float4*)&W[(k + kk) * 128 + c0 + 4];
            }
#pragma unroll
            for (int kk = 0; kk < 4; kk++) {
                float wv[8] = {wr[kk][0].x, wr[kk][0].y, wr[kk][0].z, wr[kk][0].w,
                               wr[kk][1].x, wr[kk][1].y, wr[kk][1].z, wr[kk][1].w};
#pragma unroll
                for (int i = 0; i < 4; i++) {
                    float xv = ((const float*)&xa[i])[kk];
#pragma unroll
                    for (int j = 0; j < 8; j++) acc[i][j] = fmaf(xv, wv[j], acc[i][j]);
                }
            }
        }
        float bb[8];
        *(float4*)&bb[0] = *(const float4*)&bm[w][c0];
        *(float4*)&bb[4] = *(const float4*)&bm[w][c0 + 4];
        if (w == 0 || w == 3) {
            float* om = (w == 0) ? qo : xro;
#pragma unroll
            for (int i = 0; i < 4; i++) {
                int node = m0 + mb + i;
                if (node < NN) {
                    float4 o0 = make_float4(acc[i][0] + bb[0], acc[i][1] + bb[1],
                                            acc[i][2] + bb[2], acc[i][3] + bb[3]);
                    float4 o1 = make_float4(acc[i][4] + bb[4], acc[i][5] + bb[5],
                                            acc[i][6] + bb[6], acc[i][7] + bb[7]);
                    *(float4*)&om[(size_t)node * 128 + c0] = o0;
                    *(float4*)&om[(size_t)node * 128 + c0 + 4] = o1;
                }
            }
        } else if (w == 1) {
#pragma unroll
            for (int i = 0; i < 4; i++)
#pragma unroll
                for (int j = 0; j < 4; j++)
                    khold[i][j] = __float22half2_rn(
                        make_float2(acc[i][2 * j] + bb[2 * j], acc[i][2 * j + 1] + bb[2 * j + 1]));
        } else {  // w == 2: interleaved {k0,k1,v0,v1} per channel pair
#pragma unroll
            for (int i = 0; i < 4; i++) {
                int node = m0 + mb + i;
                if (node < NN) {
#pragma unroll
                    for (int j = 0; j < 4; j++) {
                        kv8 p;
                        p.k2 = khold[i][j];
                        p.v2 = __float22half2_rn(
                            make_float2(acc[i][2 * j] + bb[2 * j], acc[i][2 * j + 1] + bb[2 * j + 1]));
                        *(kv8*)&kvh[(size_t)node * 256 + 2 * c0 + 4 * j] = p;
                    }
                }
            }
        }
    }
}

// ---------------- attention + gate + BN-stats (one wave per dst node) ----------------
// Round-5 structure: cooperative lane-load of CSR src/attr, full groups of 8 gathers
// in flight + scalar tail. (Best measured variant: 186us, VGPR 48.)
__global__ __launch_bounds__(256) void k_attn(
    const float* __restrict__ q, const __half* __restrict__ kvh,
    const float* __restrict__ xr,
    const int* __restrict__ esrc, const float* __restrict__ eat2,
    const int* __restrict__ row_ptr,
    const float* __restrict__ We, const float* __restrict__ be,
    const float* __restrict__ Wb,
    float* __restrict__ out2, float* __restrict__ bn_accum)
{
    int t = threadIdx.x;
    int lane = t & 63;
    int wid = t >> 6;
    int gwave = blockIdx.x * 4 + wid;
    int nwaves = gridDim.x * 4;
    int ch = lane * 2;
    size_t lane8 = 4 * lane;           // half offset within a node's 256-half kv row
    float2 we0 = *(const float2*)&We[ch];
    float2 we1 = *(const float2*)&We[128 + ch];
    float2 beL = *(const float2*)&be[ch];
    float2 wb_o = *(const float2*)&Wb[ch];
    float2 wb_r = *(const float2*)&Wb[128 + ch];
    float2 wb_d = *(const float2*)&Wb[256 + ch];
    const float scale = 0.17677669529663687f;   // 1/sqrt(32)
    float bnsx = 0.f, bnsy = 0.f, bnqx = 0.f, bnqy = 0.f;

    for (int n = gwave; n < NN; n += nwaves) {
        int rs = __builtin_amdgcn_readfirstlane(row_ptr[n]);
        int re = __builtin_amdgcn_readfirstlane(row_ptr[n + 1]);
        float2 qv = *(const float2*)&q[(size_t)n * 128 + ch];
        float den = 0.f;
        float ax = 0.f, ay = 0.f;

        auto edge = [&](float eax, float eay, kv8 kk) {
            float ex_ = fmaf(eax, we0.x, fmaf(eay, we1.x, beL.x));
            float ey_ = fmaf(eax, we0.y, fmaf(eay, we1.y, beL.y));
            float2 kf = __half22float2(kk.k2);
            float2 vf = __half22float2(kk.v2);
            float p = qv.x * (kf.x + ex_) + qv.y * (kf.y + ey_);
            p += __shfl_xor(p, 1);
            p += __shfl_xor(p, 2);
            p += __shfl_xor(p, 4);
            p += __shfl_xor(p, 8);
            float exv = __expf(p * scale);
            den += exv;
            ax = fmaf(exv, vf.x + ex_, ax);
            ay = fmaf(exv, vf.y + ey_, ay);
        };

        for (int cb = rs; cb < re; cb += 64) {
            int cnum = re - cb; if (cnum > 64) cnum = 64;
            int mi = cb + lane;
            int sv = 0;
            float2 av = make_float2(0.f, 0.f);
            if (mi < re) {
                sv = esrc[mi];
                av = *(const float2*)&eat2[2 * (size_t)mi];
            }
            int base = 0;
            for (; base + 8 <= cnum; base += 8) {
                int s[8]; float eax[8], eay[8];
#pragma unroll
                for (int j = 0; j < 8; j++) {
                    s[j] = __shfl(sv, base + j);
                    eax[j] = __shfl(av.x, base + j);
                    eay[j] = __shfl(av.y, base + j);
                }
                kv8 kk[8];
#pragma unroll
                for (int j = 0; j < 8; j++)
                    kk[j] = *(const kv8*)&kvh[(size_t)s[j] * 256 + lane8];
#pragma unroll
                for (int j = 0; j < 8; j++) edge(eax[j], eay[j], kk[j]);
            }
            for (; base < cnum; ++base) {
                int s0 = __shfl(sv, base);
                float ex0 = __shfl(av.x, base);
                float ey0 = __shfl(av.y, base);
                kv8 k0 = *(const kv8*)&kvh[(size_t)s0 * 256 + lane8];
                edge(ex0, ey0, k0);
            }
        }

        float rden = 1.f / (den + 1e-16f);
        ax *= rden; ay *= rden;
        // beta gate
        float2 xv = *(const float2*)&xr[(size_t)n * 128 + ch];
        float gp = ax * wb_o.x + ay * wb_o.y + xv.x * wb_r.x + xv.y * wb_r.y
                 + (ax - xv.x) * wb_d.x + (ay - xv.y) * wb_d.y;
        gp += __shfl_xor(gp, 1);
        gp += __shfl_xor(gp, 2);
        gp += __shfl_xor(gp, 4);
        gp += __shfl_xor(gp, 8);
        gp += __shfl_xor(gp, 16);
        gp += __shfl_xor(gp, 32);
        float gate = 1.f / (1.f + __expf(-gp));
        float ox = gate * xv.x + (1.f - gate) * ax;
        float oy = gate * xv.y + (1.f - gate) * ay;
        *(float2*)&out2[(size_t)n * 128 + ch] = make_float2(ox, oy);
        bnsx += ox; bnsy += oy;
        bnqx = fmaf(ox, ox, bnqx); bnqy = fmaf(oy, oy, bnqy);
    }
    // block-level BN partial reduce
    __shared__ float s_sum[2][256], s_sq[2][256];
    s_sum[0][t] = bnsx; s_sum[1][t] = bnsy;
    s_sq[0][t] = bnqx;  s_sq[1][t] = bnqy;
    __syncthreads();
    if (t < 64) {
        float sx = s_sum[0][t] + s_sum[0][64 + t] + s_sum[0][128 + t] + s_sum[0][192 + t];
        float sy = s_sum[1][t] + s_sum[1][64 + t] + s_sum[1][128 + t] + s_sum[1][192 + t];
        float qx = s_sq[0][t] + s_sq[0][64 + t] + s_sq[0][128 + t] + s_sq[0][192 + t];
        float qy = s_sq[1][t] + s_sq[1][64 + t] + s_sq[1][128 + t] + s_sq[1][192 + t];
        int c = 2 * t;
        atomicAdd(&bn_accum[c], sx);
        atomicAdd(&bn_accum[c + 1], sy);
        atomicAdd(&bn_accum[128 + c], qx);
        atomicAdd(&bn_accum[128 + c + 1], qy);
    }
}

// ------- readout: BN affine+ELU+dot(Wout), LDS per-graph accumulate, one flush per block -------
__global__ __launch_bounds__(256) void k_pool(const float* __restrict__ x,
                                              const float* __restrict__ bn_acc,
                                              const float* __restrict__ gamma,
                                              const float* __restrict__ beta,
                                              const float* __restrict__ Wout,
                                              const int* __restrict__ batch,
                                              float* __restrict__ gsum, int* __restrict__ gcnt) {
    __shared__ float lsum[NGRAPH];
    __shared__ int lcnt[NGRAPH];
    __shared__ float ab_s[256];
    int t = threadIdx.x;
    if (t < NGRAPH) { lsum[t] = 0.f; lcnt[t] = 0; }
    if (t < 128) {
        float mu = bn_acc[t] * (1.f / NN);
        float var = bn_acc[128 + t] * (1.f / NN) - mu * mu;
        float inv = rsqrtf(var + 1e-5f);
        float a = inv * gamma[t];
        ab_s[t] = a;
        ab_s[128 + t] = beta[t] - mu * a;
    }
    __syncthreads();
    int lane = t & 63;
    int wid = t >> 6;
    int ch = lane * 2;
    float2 wo = *(const float2*)&Wout[ch];
    float2 a = *(const float2*)&ab_s[ch];
    float2 b = *(const float2*)&ab_s[128 + ch];
    int base = blockIdx.x * 16 + wid * 4;
#pragma unroll
    for (int i = 0; i < 4; i++) {
        int n = base + i;
        if (n < NN) {
            float2 xv = *(const float2*)&x[(size_t)n * 128 + ch];
            float z0 = fmaf(xv.x, a.x, b.x); z0 = z0 > 0.f ? z0 : expm1f(z0);
            float z1 = fmaf(xv.y, a.y, b.y); z1 = z1 > 0.f ? z1 : expm1f(z1);
            float p = z0 * wo.x + z1 * wo.y;
            p += __shfl_xor(p, 1);
            p += __shfl_xor(p, 2);
            p += __shfl_xor(p, 4);
            p += __shfl_xor(p, 8);
            p += __shfl_xor(p, 16);
            p += __shfl_xor(p, 32);
            if (lane == 0) {
                int g = batch[n];
                atomicAdd(&lsum[g], p);
                atomicAdd(&lcnt[g], 1);
            }
        }
    }
    __syncthreads();
    if (t < NGRAPH && lcnt[t] > 0) {
        atomicAdd(&gsum[t], lsum[t]);
        atomicAdd(&gcnt[t], lcnt[t]);
    }
}

__global__ void k_final(const float* __restrict__ gsum, const int* __restrict__ gcnt,
                        const float* __restrict__ bout, const float* __restrict__ obias,
                        float* __restrict__ out) {
    int g = threadIdx.x;
    if (g < NGRAPH) out[g] = gsum[g] / fmaxf((float)gcnt[g], 1.f) + bout[0] + obias[0];
}

extern "C" void kernel_launch(void* const* d_in, const int* in_sizes, int n_in,
                              void* d_out, int out_size, void* d_ws, size_t ws_size,
                              hipStream_t stream) {
    const float* x_in       = (const float*)d_in[0];
    const int* eidx         = (const int*)d_in[1];
    const float* eattr      = (const float*)d_in[2];
    const int* batch        = (const int*)d_in[3];
    const float* Wq         = (const float*)d_in[4];
    const float* bq         = (const float*)d_in[5];
    const float* Wk         = (const float*)d_in[6];
    const float* bk         = (const float*)d_in[7];
    const float* Wv         = (const float*)d_in[8];
    const float* bv         = (const float*)d_in[9];
    const float* We         = (const float*)d_in[10];
    const float* be         = (const float*)d_in[11];
    const float* Wskip      = (const float*)d_in[12];
    const float* bskip      = (const float*)d_in[13];
    const float* Wbeta      = (const float*)d_in[14];
    const float* bn_gamma   = (const float*)d_in[15];
    const float* bn_beta    = (const float*)d_in[16];
    const float* Wout       = (const float*)d_in[17];
    const float* bout       = (const float*)d_in[18];
    const float* obias      = (const float*)d_in[19];
    float* out = (float*)d_out;

    char* ws = (char*)d_ws;
    size_t off = 0;
    auto alloc = [&](size_t bytes) -> void* {
        off = (off + 255) & ~(size_t)255;
        void* p = ws + off;
        off += bytes;
        return p;
    };
    const size_t NF = (size_t)NN * 128 * sizeof(float);
    float* xbuf    = (float*)alloc(NF);
    float* qb      = (float*)alloc(NF);
    float* xrb     = (float*)alloc(NF);
    __half* kvh    = (__half*)alloc((size_t)NN * 256 * sizeof(__half));
    int* row_ptr   = (int*)alloc((NN + 1) * sizeof(int));
    int* cnt       = (int*)alloc(NN * sizeof(int));
    int* esrc      = (int*)alloc(EE * sizeof(int));
    float* eat2    = (float*)alloc((size_t)EE * 2 * sizeof(float));
    float* bn_acc3 = (float*)alloc(3 * 256 * sizeof(float));
    float* gsum    = (float*)alloc(64 * sizeof(float));
    int* gcnt      = (int*)alloc(64 * sizeof(int));
    (void)ws_size; (void)n_in; (void)in_sizes; (void)out_size;

    // ---- CSR build (dst -> src, eattr reordered) + zero aux buffers ----
    hipMemsetAsync(cnt, 0, NN * sizeof(int), stream);
    k_deg<<<(EE + 255) / 256, 256, 0, stream>>>(eidx, cnt);
    k_scan<<<1, 1024, 0, stream>>>(cnt, row_ptr, bn_acc3, gsum, gcnt);
    k_scatter<<<(EE + 255) / 256, 256, 0, stream>>>(eidx, eattr, row_ptr, cnt, esrc, eat2);

    // ---- layers ----
    for (int l = 0; l < 3; ++l) {
        const float* Xl = (l == 0) ? x_in : xbuf;
        const float* prev_acc = (l == 0) ? bn_acc3 : bn_acc3 + (l - 1) * 256;
        k_gemm4<<<(NN + 63) / 64, 256, 0, stream>>>(
            Xl,
            Wq + (size_t)l * 16384, bq + l * 128,
            Wk + (size_t)l * 16384, bk + l * 128,
            Wv + (size_t)l * 16384, bv + l * 128,
            Wskip + (size_t)l * 16384, bskip + l * 128,
            prev_acc, bn_gamma + (l == 0 ? 0 : (l - 1) * 128),
            bn_beta + (l == 0 ? 0 : (l - 1) * 128), (l == 0) ? 0 : 1,
            qb, kvh, xrb);
        k_attn<<<3125, 256, 0, stream>>>(
            qb, kvh, xrb, esrc, eat2, row_ptr,
            We + (size_t)l * 256, be + l * 128, Wbeta + (size_t)l * 384,
            xbuf, bn_acc3 + l * 256);
    }

    // ---- readout (BN affine+ELU of layer-2 fused in) ----
    k_pool<<<(NN + 15) / 16, 256, 0, stream>>>(xbuf, bn_acc3 + 2 * 256,
                                               bn_gamma + 2 * 128, bn_beta + 2 * 128,
                                               Wout, batch, gsum, gcnt);
    k_final<<<1, 64, 0, stream>>>(gsum, gcnt, bout, obias, out);
}

// Round 9
// 1035.487 us; speedup vs baseline: 1.3905x; 1.2395x over previous
//
#include <hip/hip_runtime.h>
#include <hip/hip_fp16.h>
#include <math.h>

#define NN 50000
#define EE 800000
#define HIDDEN 128
#define NGRAPH 50

struct __align__(8) kv8 { __half2 k2, v2; };

typedef _Float16 half8 __attribute__((ext_vector_type(8)));
typedef float f32x4 __attribute__((ext_vector_type(4)));

// ---------------- CSR build ----------------
__global__ void k_deg(const int* __restrict__ eidx, int* __restrict__ cnt) {
    int e = blockIdx.x * blockDim.x + threadIdx.x;
    if (e < EE) atomicAdd(&cnt[eidx[EE + e]], 1);
}

// scan + housekeeping: exclusive-scan deg->row_ptr (4 elems/thread), zero cnt,
// zero bn_acc3 / gsum / gcnt
__global__ void k_scan(int* __restrict__ cnt, int* __restrict__ row_ptr,
                       float* __restrict__ bn_acc3, float* __restrict__ gsum,
                       int* __restrict__ gcnt) {
    __shared__ int wsum[16];
    __shared__ int carry_s;
    int t = threadIdx.x;
    int lane = t & 63, w = t >> 6;
    if (t < 768) bn_acc3[t] = 0.f;
    if (t < 64) { gsum[t] = 0.f; gcnt[t] = 0; }
    if (t == 0) carry_s = 0;
    __syncthreads();
    for (int base = 0; base < NN; base += 4096) {
        int i0 = base + t * 4;
        int v[4];
#pragma unroll
        for (int j = 0; j < 4; j++) v[j] = (i0 + j < NN) ? cnt[i0 + j] : 0;
        int s4 = v[0] + v[1] + v[2] + v[3];
        int s = s4;
#pragma unroll
        for (int o = 1; o < 64; o <<= 1) {
            int u = __shfl_up(s, o);
            if (lane >= o) s += u;
        }
        if (lane == 63) wsum[w] = s;
        __syncthreads();
        if (w == 0) {
            int ws = (lane < 16) ? wsum[lane] : 0;
#pragma unroll
            for (int o = 1; o < 16; o <<= 1) {
                int u = __shfl_up(ws, o);
                if (lane >= o) ws += u;
            }
            if (lane < 16) wsum[lane] = ws;
        }
        __syncthreads();
        int wpre = (w == 0) ? 0 : wsum[w - 1];
        int run = carry_s + wpre + s - s4;
#pragma unroll
        for (int j = 0; j < 4; j++) {
            if (i0 + j < NN) { row_ptr[i0 + j] = run; cnt[i0 + j] = 0; run += v[j]; }
        }
        __syncthreads();
        if (t == 0) carry_s += wsum[15];
        __syncthreads();
    }
    if (t == 0) row_ptr[NN] = carry_s;
}

// scatter: build CSR-ordered src-index and edge-attr arrays
__global__ void k_scatter(const int* __restrict__ eidx, const float* __restrict__ eattr,
                          const int* __restrict__ row_ptr,
                          int* __restrict__ cur, int* __restrict__ esrc, float* __restrict__ eat2) {
    int e = blockIdx.x * blockDim.x + threadIdx.x;
    if (e < EE) {
        int d = eidx[EE + e];
        int s = eidx[e];
        int p = atomicAdd(&cur[d], 1);
        int pos = row_ptr[d] + p;
        esrc[pos] = s;
        float2 ea = *(const float2*)&eattr[2 * (size_t)e];
        *(float2*)&eat2[2 * (size_t)pos] = ea;
    }
}

// ---- weight prep: transpose all 12 W (3 layers x {q,k,v,skip}) to fp16 wt[mat][n][k] ----
__global__ void k_prep(const float* __restrict__ Wq, const float* __restrict__ Wk,
                       const float* __restrict__ Wv, const float* __restrict__ Ws,
                       _Float16* __restrict__ wt) {
    int idx = blockIdx.x * 256 + threadIdx.x;   // 12 * 16384
    if (idx < 12 * 16384) {
        int mat = idx >> 14;
        int l = mat >> 2, w = mat & 3;
        int nk = idx & 16383;
        int n = nk >> 7, k = nk & 127;
        const float* W = (w == 0 ? Wq : w == 1 ? Wk : w == 2 ? Wv : Ws) + (size_t)l * 16384;
        wt[idx] = (_Float16)W[k * 128 + n];
    }
}

// ---- fused 4-way GEMM via f16 MFMA: q,xr fp32 out; k,v packed fp16 interleaved.
// When use_ab: BN affine+ELU applied to input X (stats from bn_acc) during staging.
// Layouts (gfx950 v_mfma_f32_16x16x32_f16): A[m=lane&15][k=quad*8+j],
// B[k=quad*8+j][n=lane&15], D col=lane&15 row=quad*4+reg.
__global__ __launch_bounds__(256) void k_gemm4(
    const float* __restrict__ X, const _Float16* __restrict__ wt,
    const float* __restrict__ bq, const float* __restrict__ bk,
    const float* __restrict__ bv, const float* __restrict__ bs,
    const float* __restrict__ bn_acc, const float* __restrict__ gamma,
    const float* __restrict__ beta, int use_ab,
    float* __restrict__ qo, __half* __restrict__ kvh, float* __restrict__ xro)
{
    __shared__ _Float16 xs[64][136];
    __shared__ float ab_s[256];
    int t = threadIdx.x;
    int m0 = blockIdx.x * 64;
    if (use_ab) {
        if (t < 128) {
            float mu = bn_acc[t] * (1.f / NN);
            float var = bn_acc[128 + t] * (1.f / NN) - mu * mu;
            float inv = rsqrtf(var + 1e-5f);
            float a = inv * gamma[t];
            ab_s[t] = a;
            ab_s[128 + t] = beta[t] - mu * a;
        }
        __syncthreads();
    }
#pragma unroll
    for (int i = 0; i < 8; ++i) {
        int f = t + 256 * i;          // float4 index within 64x32
        int r = f >> 5, c4 = (f & 31) << 2;
        float4 val = make_float4(0.f, 0.f, 0.f, 0.f);
        if (m0 + r < NN) val = *(const float4*)&X[(size_t)(m0 + r) * 128 + c4];
        if (use_ab) {
            float4 a = *(const float4*)&ab_s[c4];
            float4 bb = *(const float4*)&ab_s[128 + c4];
            float z;
            z = fmaf(val.x, a.x, bb.x); val.x = z > 0.f ? z : expm1f(z);
            z = fmaf(val.y, a.y, bb.y); val.y = z > 0.f ? z : expm1f(z);
            z = fmaf(val.z, a.z, bb.z); val.z = z > 0.f ? z : expm1f(z);
            z = fmaf(val.w, a.w, bb.w); val.w = z > 0.f ? z : expm1f(z);
        }
        _Float16* dst = &xs[r][c4];
        dst[0] = (_Float16)val.x; dst[1] = (_Float16)val.y;
        dst[2] = (_Float16)val.z; dst[3] = (_Float16)val.w;
    }
    __syncthreads();
    int lane = t & 63, wid = t >> 6;
    int quad = lane >> 4, l15 = lane & 15;
    int mrow = wid * 16;
    half8 afrag[4];
#pragma unroll
    for (int kk = 0; kk < 4; kk++)
        afrag[kk] = *(const half8*)&xs[mrow + l15][kk * 32 + quad * 8];

#pragma unroll
    for (int nt = 0; nt < 8; nt++) {
        int c = nt * 16 + l15;
        f32x4 acc[4];
#pragma unroll
        for (int w = 0; w < 4; w++) acc[w] = (f32x4){0.f, 0.f, 0.f, 0.f};
#pragma unroll
        for (int kk = 0; kk < 4; kk++) {
            half8 bf[4];
#pragma unroll
            for (int w = 0; w < 4; w++)
                bf[w] = *(const half8*)&wt[(size_t)w * 16384 + c * 128 + kk * 32 + quad * 8];
#pragma unroll
            for (int w = 0; w < 4; w++)
                acc[w] = __builtin_amdgcn_mfma_f32_16x16x32_f16(afrag[kk], bf[w], acc[w], 0, 0, 0);
        }
        float bqv = bq[c], bkv = bk[c], bvv = bv[c], bsv = bs[c];
        int nodebase = m0 + mrow + quad * 4;
#pragma unroll
        for (int r = 0; r < 4; r++) {
            int node = nodebase + r;
            bool ok = node < NN;
            float qv = acc[0][r] + bqv;
            float xv = acc[3][r] + bsv;
            float kf = acc[1][r] + bkv;
            float vf = acc[2][r] + bvv;
            float kf1 = __shfl_xor(kf, 1);
            float vf1 = __shfl_xor(vf, 1);
            if (ok) {
                qo[(size_t)node * 128 + c] = qv;
                xro[(size_t)node * 128 + c] = xv;
                if (!(lane & 1)) {
                    kv8 p;
                    p.k2 = __floats2half2_rn(kf, kf1);
                    p.v2 = __floats2half2_rn(vf, vf1);
                    *(kv8*)&kvh[(size_t)node * 256 + 2 * c] = p;
                }
            }
        }
    }
}

// ---------------- attention + gate + BN-stats (one wave per dst node) ----------------
// Round-5 structure: cooperative lane-load of CSR src/attr, full groups of 8 gathers
// in flight + scalar tail. (Best measured variant: 186us, VGPR 48.)
__global__ __launch_bounds__(256) void k_attn(
    const float* __restrict__ q, const __half* __restrict__ kvh,
    const float* __restrict__ xr,
    const int* __restrict__ esrc, const float* __restrict__ eat2,
    const int* __restrict__ row_ptr,
    const float* __restrict__ We, const float* __restrict__ be,
    const float* __restrict__ Wb,
    float* __restrict__ out2, float* __restrict__ bn_accum)
{
    int t = threadIdx.x;
    int lane = t & 63;
    int wid = t >> 6;
    int gwave = blockIdx.x * 4 + wid;
    int nwaves = gridDim.x * 4;
    int ch = lane * 2;
    size_t lane8 = 4 * lane;           // half offset within a node's 256-half kv row
    float2 we0 = *(const float2*)&We[ch];
    float2 we1 = *(const float2*)&We[128 + ch];
    float2 beL = *(const float2*)&be[ch];
    float2 wb_o = *(const float2*)&Wb[ch];
    float2 wb_r = *(const float2*)&Wb[128 + ch];
    float2 wb_d = *(const float2*)&Wb[256 + ch];
    const float scale = 0.17677669529663687f;   // 1/sqrt(32)
    float bnsx = 0.f, bnsy = 0.f, bnqx = 0.f, bnqy = 0.f;

    for (int n = gwave; n < NN; n += nwaves) {
        int rs = __builtin_amdgcn_readfirstlane(row_ptr[n]);
        int re = __builtin_amdgcn_readfirstlane(row_ptr[n + 1]);
        float2 qv = *(const float2*)&q[(size_t)n * 128 + ch];
        float den = 0.f;
        float ax = 0.f, ay = 0.f;

        auto edge = [&](float eax, float eay, kv8 kk) {
            float ex_ = fmaf(eax, we0.x, fmaf(eay, we1.x, beL.x));
            float ey_ = fmaf(eax, we0.y, fmaf(eay, we1.y, beL.y));
            float2 kf = __half22float2(kk.k2);
            float2 vf = __half22float2(kk.v2);
            float p = qv.x * (kf.x + ex_) + qv.y * (kf.y + ey_);
            p += __shfl_xor(p, 1);
            p += __shfl_xor(p, 2);
            p += __shfl_xor(p, 4);
            p += __shfl_xor(p, 8);
            float exv = __expf(p * scale);
            den += exv;
            ax = fmaf(exv, vf.x + ex_, ax);
            ay = fmaf(exv, vf.y + ey_, ay);
        };

        for (int cb = rs; cb < re; cb += 64) {
            int cnum = re - cb; if (cnum > 64) cnum = 64;
            int mi = cb + lane;
            int sv = 0;
            float2 av = make_float2(0.f, 0.f);
            if (mi < re) {
                sv = esrc[mi];
                av = *(const float2*)&eat2[2 * (size_t)mi];
            }
            int base = 0;
            for (; base + 8 <= cnum; base += 8) {
                int s[8]; float eax[8], eay[8];
#pragma unroll
                for (int j = 0; j < 8; j++) {
                    s[j] = __shfl(sv, base + j);
                    eax[j] = __shfl(av.x, base + j);
                    eay[j] = __shfl(av.y, base + j);
                }
                kv8 kk[8];
#pragma unroll
                for (int j = 0; j < 8; j++)
                    kk[j] = *(const kv8*)&kvh[(size_t)s[j] * 256 + lane8];
#pragma unroll
                for (int j = 0; j < 8; j++) edge(eax[j], eay[j], kk[j]);
            }
            for (; base < cnum; ++base) {
                int s0 = __shfl(sv, base);
                float ex0 = __shfl(av.x, base);
                float ey0 = __shfl(av.y, base);
                kv8 k0 = *(const kv8*)&kvh[(size_t)s0 * 256 + lane8];
                edge(ex0, ey0, k0);
            }
        }

        float rden = 1.f / (den + 1e-16f);
        ax *= rden; ay *= rden;
        // beta gate
        float2 xv = *(const float2*)&xr[(size_t)n * 128 + ch];
        float gp = ax * wb_o.x + ay * wb_o.y + xv.x * wb_r.x + xv.y * wb_r.y
                 + (ax - xv.x) * wb_d.x + (ay - xv.y) * wb_d.y;
        gp += __shfl_xor(gp, 1);
        gp += __shfl_xor(gp, 2);
        gp += __shfl_xor(gp, 4);
        gp += __shfl_xor(gp, 8);
        gp += __shfl_xor(gp, 16);
        gp += __shfl_xor(gp, 32);
        float gate = 1.f / (1.f + __expf(-gp));
        float ox = gate * xv.x + (1.f - gate) * ax;
        float oy = gate * xv.y + (1.f - gate) * ay;
        *(float2*)&out2[(size_t)n * 128 + ch] = make_float2(ox, oy);
        bnsx += ox; bnsy += oy;
        bnqx = fmaf(ox, ox, bnqx); bnqy = fmaf(oy, oy, bnqy);
    }
    // block-level BN partial reduce
    __shared__ float s_sum[2][256], s_sq[2][256];
    s_sum[0][t] = bnsx; s_sum[1][t] = bnsy;
    s_sq[0][t] = bnqx;  s_sq[1][t] = bnqy;
    __syncthreads();
    if (t < 64) {
        float sx = s_sum[0][t] + s_sum[0][64 + t] + s_sum[0][128 + t] + s_sum[0][192 + t];
        float sy = s_sum[1][t] + s_sum[1][64 + t] + s_sum[1][128 + t] + s_sum[1][192 + t];
        float qx = s_sq[0][t] + s_sq[0][64 + t] + s_sq[0][128 + t] + s_sq[0][192 + t];
        float qy = s_sq[1][t] + s_sq[1][64 + t] + s_sq[1][128 + t] + s_sq[1][192 + t];
        int c = 2 * t;
        atomicAdd(&bn_accum[c], sx);
        atomicAdd(&bn_accum[c + 1], sy);
        atomicAdd(&bn_accum[128 + c], qx);
        atomicAdd(&bn_accum[128 + c + 1], qy);
    }
}

// ------- readout: BN affine+ELU+dot(Wout), LDS per-graph accumulate, one flush per block -------
__global__ __launch_bounds__(256) void k_pool(const float* __restrict__ x,
                                              const float* __restrict__ bn_acc,
                                              const float* __restrict__ gamma,
                                              const float* __restrict__ beta,
                                              const float* __restrict__ Wout,
                                              const int* __restrict__ batch,
                                              float* __restrict__ gsum, int* __restrict__ gcnt) {
    __shared__ float lsum[NGRAPH];
    __shared__ int lcnt[NGRAPH];
    __shared__ float ab_s[256];
    int t = threadIdx.x;
    if (t < NGRAPH) { lsum[t] = 0.f; lcnt[t] = 0; }
    if (t < 128) {
        float mu = bn_acc[t] * (1.f / NN);
        float var = bn_acc[128 + t] * (1.f / NN) - mu * mu;
        float inv = rsqrtf(var + 1e-5f);
        float a = inv * gamma[t];
        ab_s[t] = a;
        ab_s[128 + t] = beta[t] - mu * a;
    }
    __syncthreads();
    int lane = t & 63;
    int wid = t >> 6;
    int ch = lane * 2;
    float2 wo = *(const float2*)&Wout[ch];
    float2 a = *(const float2*)&ab_s[ch];
    float2 b = *(const float2*)&ab_s[128 + ch];
    int base = blockIdx.x * 16 + wid * 4;
#pragma unroll
    for (int i = 0; i < 4; i++) {
        int n = base + i;
        if (n < NN) {
            float2 xv = *(const float2*)&x[(size_t)n * 128 + ch];
            float z0 = fmaf(xv.x, a.x, b.x); z0 = z0 > 0.f ? z0 : expm1f(z0);
            float z1 = fmaf(xv.y, a.y, b.y); z1 = z1 > 0.f ? z1 : expm1f(z1);
            float p = z0 * wo.x + z1 * wo.y;
            p += __shfl_xor(p, 1);
            p += __shfl_xor(p, 2);
            p += __shfl_xor(p, 4);
            p += __shfl_xor(p, 8);
            p += __shfl_xor(p, 16);
            p += __shfl_xor(p, 32);
            if (lane == 0) {
                int g = batch[n];
                atomicAdd(&lsum[g], p);
                atomicAdd(&lcnt[g], 1);
            }
        }
    }
    __syncthreads();
    if (t < NGRAPH && lcnt[t] > 0) {
        atomicAdd(&gsum[t], lsum[t]);
        atomicAdd(&gcnt[t], lcnt[t]);
    }
}

__global__ void k_final(const float* __restrict__ gsum, const int* __restrict__ gcnt,
                        const float* __restrict__ bout, const float* __restrict__ obias,
                        float* __restrict__ out) {
    int g = threadIdx.x;
    if (g < NGRAPH) out[g] = gsum[g] / fmaxf((float)gcnt[g], 1.f) + bout[0] + obias[0];
}

extern "C" void kernel_launch(void* const* d_in, const int* in_sizes, int n_in,
                              void* d_out, int out_size, void* d_ws, size_t ws_size,
                              hipStream_t stream) {
    const float* x_in       = (const float*)d_in[0];
    const int* eidx         = (const int*)d_in[1];
    const float* eattr      = (const float*)d_in[2];
    const int* batch        = (const int*)d_in[3];
    const float* Wq         = (const float*)d_in[4];
    const float* bq         = (const float*)d_in[5];
    const float* Wk         = (const float*)d_in[6];
    const float* bk         = (const float*)d_in[7];
    const float* Wv         = (const float*)d_in[8];
    const float* bv         = (const float*)d_in[9];
    const float* We         = (const float*)d_in[10];
    const float* be         = (const float*)d_in[11];
    const float* Wskip      = (const float*)d_in[12];
    const float* bskip      = (const float*)d_in[13];
    const float* Wbeta      = (const float*)d_in[14];
    const float* bn_gamma   = (const float*)d_in[15];
    const float* bn_beta    = (const float*)d_in[16];
    const float* Wout       = (const float*)d_in[17];
    const float* bout       = (const float*)d_in[18];
    const float* obias      = (const float*)d_in[19];
    float* out = (float*)d_out;

    char* ws = (char*)d_ws;
    size_t off = 0;
    auto alloc = [&](size_t bytes) -> void* {
        off = (off + 255) & ~(size_t)255;
        void* p = ws + off;
        off += bytes;
        return p;
    };
    const size_t NF = (size_t)NN * 128 * sizeof(float);
    float* xbuf    = (float*)alloc(NF);
    float* qb      = (float*)alloc(NF);
    float* xrb     = (float*)alloc(NF);
    __half* kvh    = (__half*)alloc((size_t)NN * 256 * sizeof(__half));
    _Float16* wt   = (_Float16*)alloc((size_t)12 * 16384 * sizeof(_Float16));
    int* row_ptr   = (int*)alloc((NN + 1) * sizeof(int));
    int* cnt       = (int*)alloc(NN * sizeof(int));
    int* esrc      = (int*)alloc(EE * sizeof(int));
    float* eat2    = (float*)alloc((size_t)EE * 2 * sizeof(float));
    float* bn_acc3 = (float*)alloc(3 * 256 * sizeof(float));
    float* gsum    = (float*)alloc(64 * sizeof(float));
    int* gcnt      = (int*)alloc(64 * sizeof(int));
    (void)ws_size; (void)n_in; (void)in_sizes; (void)out_size;

    // ---- CSR build (dst -> src, eattr reordered) + zero aux buffers + weight prep ----
    hipMemsetAsync(cnt, 0, NN * sizeof(int), stream);
    k_deg<<<(EE + 255) / 256, 256, 0, stream>>>(eidx, cnt);
    k_scan<<<1, 1024, 0, stream>>>(cnt, row_ptr, bn_acc3, gsum, gcnt);
    k_scatter<<<(EE + 255) / 256, 256, 0, stream>>>(eidx, eattr, row_ptr, cnt, esrc, eat2);
    k_prep<<<768, 256, 0, stream>>>(Wq, Wk, Wv, Wskip, wt);

    // ---- layers ----
    for (int l = 0; l < 3; ++l) {
        const float* Xl = (l == 0) ? x_in : xbuf;
        const float* prev_acc = (l == 0) ? bn_acc3 : bn_acc3 + (l - 1) * 256;
        k_gemm4<<<(NN + 63) / 64, 256, 0, stream>>>(
            Xl, wt + (size_t)l * 65536,
            bq + l * 128, bk + l * 128, bv + l * 128, bskip + l * 128,
            prev_acc, bn_gamma + (l == 0 ? 0 : (l - 1) * 128),
            bn_beta + (l == 0 ? 0 : (l - 1) * 128), (l == 0) ? 0 : 1,
            qb, kvh, xrb);
        k_attn<<<3125, 256, 0, stream>>>(
            qb, kvh, xrb, esrc, eat2, row_ptr,
            We + (size_t)l * 256, be + l * 128, Wbeta + (size_t)l * 384,
            xbuf, bn_acc3 + l * 256);
    }

    // ---- readout (BN affine+ELU of layer-2 fused in) ----
    k_pool<<<(NN + 15) / 16, 256, 0, stream>>>(xbuf, bn_acc3 + 2 * 256,
                                               bn_gamma + 2 * 128, bn_beta + 2 * 128,
                                               Wout, batch, gsum, gcnt);
    k_final<<<1, 64, 0, stream>>>(gsum, gcnt, bout, obias, out);
}

// Round 10
// 1014.870 us; speedup vs baseline: 1.4187x; 1.0203x over previous
//
#include <hip/hip_runtime.h>
#include <hip/hip_fp16.h>
#include <math.h>

#define NN 50000
#define EE 800000
#define HIDDEN 128
#define NGRAPH 50

typedef _Float16 half8 __attribute__((ext_vector_type(8)));
typedef float f32x4 __attribute__((ext_vector_type(4)));

// ---------------- CSR degree count + weight transpose (union grid) ----------------
__global__ void k_degprep(const int* __restrict__ eidx, int* __restrict__ cnt,
                          const float* __restrict__ Wq, const float* __restrict__ Wk,
                          const float* __restrict__ Wv, const float* __restrict__ Ws,
                          _Float16* __restrict__ wt) {
    int b = blockIdx.x;
    int t = threadIdx.x;
    if (b < 3125) {
        int e = b * 256 + t;
        if (e < EE) atomicAdd(&cnt[eidx[EE + e]], 1);
    } else {
        int idx = (b - 3125) * 256 + t;   // 12 * 16384 fp16 transposed weights
        if (idx < 12 * 16384) {
            int mat = idx >> 14;
            int l = mat >> 2, w = mat & 3;
            int nk = idx & 16383;
            int n = nk >> 7, k = nk & 127;
            const float* W = (w == 0 ? Wq : w == 1 ? Wk : w == 2 ? Wv : Ws) + (size_t)l * 16384;
            wt[idx] = (_Float16)W[k * 128 + n];
        }
    }
}

// scan + housekeeping: exclusive-scan deg->row_ptr (4 elems/thread), zero cnt,
// zero bn_acc3 / gsum / gcnt
__global__ void k_scan(int* __restrict__ cnt, int* __restrict__ row_ptr,
                       float* __restrict__ bn_acc3, float* __restrict__ gsum,
                       int* __restrict__ gcnt) {
    __shared__ int wsum[16];
    __shared__ int carry_s;
    int t = threadIdx.x;
    int lane = t & 63, w = t >> 6;
    if (t < 768) bn_acc3[t] = 0.f;
    if (t < 64) { gsum[t] = 0.f; gcnt[t] = 0; }
    if (t == 0) carry_s = 0;
    __syncthreads();
    for (int base = 0; base < NN; base += 4096) {
        int i0 = base + t * 4;
        int v[4];
#pragma unroll
        for (int j = 0; j < 4; j++) v[j] = (i0 + j < NN) ? cnt[i0 + j] : 0;
        int s4 = v[0] + v[1] + v[2] + v[3];
        int s = s4;
#pragma unroll
        for (int o = 1; o < 64; o <<= 1) {
            int u = __shfl_up(s, o);
            if (lane >= o) s += u;
        }
        if (lane == 63) wsum[w] = s;
        __syncthreads();
        if (w == 0) {
            int ws = (lane < 16) ? wsum[lane] : 0;
#pragma unroll
            for (int o = 1; o < 16; o <<= 1) {
                int u = __shfl_up(ws, o);
                if (lane >= o) ws += u;
            }
            if (lane < 16) wsum[lane] = ws;
        }
        __syncthreads();
        int wpre = (w == 0) ? 0 : wsum[w - 1];
        int run = carry_s + wpre + s - s4;
#pragma unroll
        for (int j = 0; j < 4; j++) {
            if (i0 + j < NN) { row_ptr[i0 + j] = run; cnt[i0 + j] = 0; run += v[j]; }
        }
        __syncthreads();
        if (t == 0) carry_s += wsum[15];
        __syncthreads();
    }
    if (t == 0) row_ptr[NN] = carry_s;
}

// scatter: build CSR-ordered src-index and edge-attr arrays
__global__ void k_scatter(const int* __restrict__ eidx, const float* __restrict__ eattr,
                          const int* __restrict__ row_ptr,
                          int* __restrict__ cur, int* __restrict__ esrc, float* __restrict__ eat2) {
    int e = blockIdx.x * blockDim.x + threadIdx.x;
    if (e < EE) {
        int d = eidx[EE + e];
        int s = eidx[e];
        int p = atomicAdd(&cur[d], 1);
        int pos = row_ptr[d] + p;
        esrc[pos] = s;
        float2 ea = *(const float2*)&eattr[2 * (size_t)e];
        *(float2*)&eat2[2 * (size_t)pos] = ea;
    }
}

// ---- fused 4-way GEMM via f16 MFMA: q,xr fp32 out; k,v packed OCP fp8 e4m3.
// When use_ab: BN affine+ELU applied to input X (stats from bn_acc) during staging.
// Layouts (gfx950 v_mfma_f32_16x16x32_f16): A[m=lane&15][k=quad*8+j],
// B[k=quad*8+j][n=lane&15], D col=lane&15 row=quad*4+reg.
__global__ __launch_bounds__(256) void k_gemm4(
    const float* __restrict__ X, const _Float16* __restrict__ wt,
    const float* __restrict__ bq, const float* __restrict__ bk,
    const float* __restrict__ bv, const float* __restrict__ bs,
    const float* __restrict__ bn_acc, const float* __restrict__ gamma,
    const float* __restrict__ beta, int use_ab,
    float* __restrict__ qo, unsigned int* __restrict__ kvb, float* __restrict__ xro)
{
    __shared__ _Float16 xs[64][136];
    __shared__ float ab_s[256];
    int t = threadIdx.x;
    int m0 = blockIdx.x * 64;
    if (use_ab) {
        if (t < 128) {
            float mu = bn_acc[t] * (1.f / NN);
            float var = bn_acc[128 + t] * (1.f / NN) - mu * mu;
            float inv = rsqrtf(var + 1e-5f);
            float a = inv * gamma[t];
            ab_s[t] = a;
            ab_s[128 + t] = beta[t] - mu * a;
        }
        __syncthreads();
    }
#pragma unroll
    for (int i = 0; i < 8; ++i) {
        int f = t + 256 * i;          // float4 index within 64x32
        int r = f >> 5, c4 = (f & 31) << 2;
        float4 val = make_float4(0.f, 0.f, 0.f, 0.f);
        if (m0 + r < NN) val = *(const float4*)&X[(size_t)(m0 + r) * 128 + c4];
        if (use_ab) {
            float4 a = *(const float4*)&ab_s[c4];
            float4 bb = *(const float4*)&ab_s[128 + c4];
            float z;
            z = fmaf(val.x, a.x, bb.x); val.x = z > 0.f ? z : expm1f(z);
            z = fmaf(val.y, a.y, bb.y); val.y = z > 0.f ? z : expm1f(z);
            z = fmaf(val.z, a.z, bb.z); val.z = z > 0.f ? z : expm1f(z);
            z = fmaf(val.w, a.w, bb.w); val.w = z > 0.f ? z : expm1f(z);
        }
        _Float16* dst = &xs[r][c4];
        dst[0] = (_Float16)val.x; dst[1] = (_Float16)val.y;
        dst[2] = (_Float16)val.z; dst[3] = (_Float16)val.w;
    }
    __syncthreads();
    int lane = t & 63, wid = t >> 6;
    int quad = lane >> 4, l15 = lane & 15;
    int mrow = wid * 16;
    half8 afrag[4];
#pragma unroll
    for (int kk = 0; kk < 4; kk++)
        afrag[kk] = *(const half8*)&xs[mrow + l15][kk * 32 + quad * 8];

#pragma unroll
    for (int nt = 0; nt < 8; nt++) {
        int c = nt * 16 + l15;
        f32x4 acc[4];
#pragma unroll
        for (int w = 0; w < 4; w++) acc[w] = (f32x4){0.f, 0.f, 0.f, 0.f};
#pragma unroll
        for (int kk = 0; kk < 4; kk++) {
            half8 bf[4];
#pragma unroll
            for (int w = 0; w < 4; w++)
                bf[w] = *(const half8*)&wt[(size_t)w * 16384 + c * 128 + kk * 32 + quad * 8];
#pragma unroll
            for (int w = 0; w < 4; w++)
                acc[w] = __builtin_amdgcn_mfma_f32_16x16x32_f16(afrag[kk], bf[w], acc[w], 0, 0, 0);
        }
        float bqv = bq[c], bkv = bk[c], bvv = bv[c], bsv = bs[c];
        int nodebase = m0 + mrow + quad * 4;
#pragma unroll
        for (int r = 0; r < 4; r++) {
            int node = nodebase + r;
            bool ok = node < NN;
            float qv = acc[0][r] + bqv;
            float xv = acc[3][r] + bsv;
            float kf = acc[1][r] + bkv;
            float vf = acc[2][r] + bvv;
            float kf1 = __shfl_xor(kf, 1);
            float vf1 = __shfl_xor(vf, 1);
            if (ok) {
                qo[(size_t)node * 128 + c] = qv;
                xro[(size_t)node * 128 + c] = xv;
                if (!(lane & 1)) {
                    // pack {k[c],k[c+1],v[c],v[c+1]} as 4x fp8 e4m3 in one word
                    int w2 = __builtin_amdgcn_cvt_pk_fp8_f32(kf, kf1, 0, false);
                    w2 = __builtin_amdgcn_cvt_pk_fp8_f32(vf, vf1, w2, true);
                    kvb[(size_t)node * 64 + (c >> 1)] = (unsigned int)w2;
                }
            }
        }
    }
}

// ---------------- attention + gate + BN-stats (one wave per dst node) ----------------
// Round-5 loop structure (best measured); kv gather is now 4B/lane fp8 (4 lines/edge).
__global__ __launch_bounds__(256) void k_attn(
    const float* __restrict__ q, const unsigned int* __restrict__ kvb,
    const float* __restrict__ xr,
    const int* __restrict__ esrc, const float* __restrict__ eat2,
    const int* __restrict__ row_ptr,
    const float* __restrict__ We, const float* __restrict__ be,
    const float* __restrict__ Wb,
    float* __restrict__ out2, float* __restrict__ bn_accum)
{
    int t = threadIdx.x;
    int lane = t & 63;
    int wid = t >> 6;
    int gwave = blockIdx.x * 4 + wid;
    int nwaves = gridDim.x * 4;
    int ch = lane * 2;
    float2 we0 = *(const float2*)&We[ch];
    float2 we1 = *(const float2*)&We[128 + ch];
    float2 beL = *(const float2*)&be[ch];
    float2 wb_o = *(const float2*)&Wb[ch];
    float2 wb_r = *(const float2*)&Wb[128 + ch];
    float2 wb_d = *(const float2*)&Wb[256 + ch];
    const float scale = 0.17677669529663687f;   // 1/sqrt(32)
    float bnsx = 0.f, bnsy = 0.f, bnqx = 0.f, bnqy = 0.f;

    for (int n = gwave; n < NN; n += nwaves) {
        int rs = __builtin_amdgcn_readfirstlane(row_ptr[n]);
        int re = __builtin_amdgcn_readfirstlane(row_ptr[n + 1]);
        float2 qv = *(const float2*)&q[(size_t)n * 128 + ch];
        float den = 0.f;
        float ax = 0.f, ay = 0.f;

        auto edge = [&](float eax, float eay, unsigned int w8) {
            auto kf = __builtin_amdgcn_cvt_pk_f32_fp8((int)w8, false);
            auto vf = __builtin_amdgcn_cvt_pk_f32_fp8((int)w8, true);
            float ex_ = fmaf(eax, we0.x, fmaf(eay, we1.x, beL.x));
            float ey_ = fmaf(eax, we0.y, fmaf(eay, we1.y, beL.y));
            float p = qv.x * (kf[0] + ex_) + qv.y * (kf[1] + ey_);
            p += __shfl_xor(p, 1);
            p += __shfl_xor(p, 2);
            p += __shfl_xor(p, 4);
            p += __shfl_xor(p, 8);
            float exv = __expf(p * scale);
            den += exv;
            ax = fmaf(exv, vf[0] + ex_, ax);
            ay = fmaf(exv, vf[1] + ey_, ay);
        };

        for (int cb = rs; cb < re; cb += 64) {
            int cnum = re - cb; if (cnum > 64) cnum = 64;
            int mi = cb + lane;
            int sv = 0;
            float2 av = make_float2(0.f, 0.f);
            if (mi < re) {
                sv = esrc[mi];
                av = *(const float2*)&eat2[2 * (size_t)mi];
            }
            int base = 0;
            for (; base + 8 <= cnum; base += 8) {
                int s[8]; float eax[8], eay[8];
#pragma unroll
                for (int j = 0; j < 8; j++) {
                    s[j] = __shfl(sv, base + j);
                    eax[j] = __shfl(av.x, base + j);
                    eay[j] = __shfl(av.y, base + j);
                }
                unsigned int kk[8];
#pragma unroll
                for (int j = 0; j < 8; j++)
                    kk[j] = kvb[(size_t)s[j] * 64 + lane];
#pragma unroll
                for (int j = 0; j < 8; j++) edge(eax[j], eay[j], kk[j]);
            }
            for (; base < cnum; ++base) {
                int s0 = __shfl(sv, base);
                float ex0 = __shfl(av.x, base);
                float ey0 = __shfl(av.y, base);
                unsigned int k0 = kvb[(size_t)s0 * 64 + lane];
                edge(ex0, ey0, k0);
            }
        }

        float rden = 1.f / (den + 1e-16f);
        ax *= rden; ay *= rden;
        // beta gate
        float2 xv = *(const float2*)&xr[(size_t)n * 128 + ch];
        float gp = ax * wb_o.x + ay * wb_o.y + xv.x * wb_r.x + xv.y * wb_r.y
                 + (ax - xv.x) * wb_d.x + (ay - xv.y) * wb_d.y;
        gp += __shfl_xor(gp, 1);
        gp += __shfl_xor(gp, 2);
        gp += __shfl_xor(gp, 4);
        gp += __shfl_xor(gp, 8);
        gp += __shfl_xor(gp, 16);
        gp += __shfl_xor(gp, 32);
        float gate = 1.f / (1.f + __expf(-gp));
        float ox = gate * xv.x + (1.f - gate) * ax;
        float oy = gate * xv.y + (1.f - gate) * ay;
        *(float2*)&out2[(size_t)n * 128 + ch] = make_float2(ox, oy);
        bnsx += ox; bnsy += oy;
        bnqx = fmaf(ox, ox, bnqx); bnqy = fmaf(oy, oy, bnqy);
    }
    // block-level BN partial reduce
    __shared__ float s_sum[2][256], s_sq[2][256];
    s_sum[0][t] = bnsx; s_sum[1][t] = bnsy;
    s_sq[0][t] = bnqx;  s_sq[1][t] = bnqy;
    __syncthreads();
    if (t < 64) {
        float sx = s_sum[0][t] + s_sum[0][64 + t] + s_sum[0][128 + t] + s_sum[0][192 + t];
        float sy = s_sum[1][t] + s_sum[1][64 + t] + s_sum[1][128 + t] + s_sum[1][192 + t];
        float qx = s_sq[0][t] + s_sq[0][64 + t] + s_sq[0][128 + t] + s_sq[0][192 + t];
        float qy = s_sq[1][t] + s_sq[1][64 + t] + s_sq[1][128 + t] + s_sq[1][192 + t];
        int c = 2 * t;
        atomicAdd(&bn_accum[c], sx);
        atomicAdd(&bn_accum[c + 1], sy);
        atomicAdd(&bn_accum[128 + c], qx);
        atomicAdd(&bn_accum[128 + c + 1], qy);
    }
}

// ------- readout: BN affine+ELU+dot(Wout), LDS per-graph accumulate, one flush per block -------
__global__ __launch_bounds__(256) void k_pool(const float* __restrict__ x,
                                              const float* __restrict__ bn_acc,
                                              const float* __restrict__ gamma,
                                              const float* __restrict__ beta,
                                              const float* __restrict__ Wout,
                                              const int* __restrict__ batch,
                                              float* __restrict__ gsum, int* __restrict__ gcnt) {
    __shared__ float lsum[NGRAPH];
    __shared__ int lcnt[NGRAPH];
    __shared__ float ab_s[256];
    int t = threadIdx.x;
    if (t < NGRAPH) { lsum[t] = 0.f; lcnt[t] = 0; }
    if (t < 128) {
        float mu = bn_acc[t] * (1.f / NN);
        float var = bn_acc[128 + t] * (1.f / NN) - mu * mu;
        float inv = rsqrtf(var + 1e-5f);
        float a = inv * gamma[t];
        ab_s[t] = a;
        ab_s[128 + t] = beta[t] - mu * a;
    }
    __syncthreads();
    int lane = t & 63;
    int wid = t >> 6;
    int ch = lane * 2;
    float2 wo = *(const float2*)&Wout[ch];
    float2 a = *(const float2*)&ab_s[ch];
    float2 b = *(const float2*)&ab_s[128 + ch];
    int base = blockIdx.x * 16 + wid * 4;
#pragma unroll
    for (int i = 0; i < 4; i++) {
        int n = base + i;
        if (n < NN) {
            float2 xv = *(const float2*)&x[(size_t)n * 128 + ch];
            float z0 = fmaf(xv.x, a.x, b.x); z0 = z0 > 0.f ? z0 : expm1f(z0);
            float z1 = fmaf(xv.y, a.y, b.y); z1 = z1 > 0.f ? z1 : expm1f(z1);
            float p = z0 * wo.x + z1 * wo.y;
            p += __shfl_xor(p, 1);
            p += __shfl_xor(p, 2);
            p += __shfl_xor(p, 4);
            p += __shfl_xor(p, 8);
            p += __shfl_xor(p, 16);
            p += __shfl_xor(p, 32);
            if (lane == 0) {
                int g = batch[n];
                atomicAdd(&lsum[g], p);
                atomicAdd(&lcnt[g], 1);
            }
        }
    }
    __syncthreads();
    if (t < NGRAPH && lcnt[t] > 0) {
        atomicAdd(&gsum[t], lsum[t]);
        atomicAdd(&gcnt[t], lcnt[t]);
    }
}

__global__ void k_final(const float* __restrict__ gsum, const int* __restrict__ gcnt,
                        const float* __restrict__ bout, const float* __restrict__ obias,
                        float* __restrict__ out) {
    int g = threadIdx.x;
    if (g < NGRAPH) out[g] = gsum[g] / fmaxf((float)gcnt[g], 1.f) + bout[0] + obias[0];
}

extern "C" void kernel_launch(void* const* d_in, const int* in_sizes, int n_in,
                              void* d_out, int out_size, void* d_ws, size_t ws_size,
                              hipStream_t stream) {
    const float* x_in       = (const float*)d_in[0];
    const int* eidx         = (const int*)d_in[1];
    const float* eattr      = (const float*)d_in[2];
    const int* batch        = (const int*)d_in[3];
    const float* Wq         = (const float*)d_in[4];
    const float* bq         = (const float*)d_in[5];
    const float* Wk         = (const float*)d_in[6];
    const float* bk         = (const float*)d_in[7];
    const float* Wv         = (const float*)d_in[8];
    const float* bv         = (const float*)d_in[9];
    const float* We         = (const float*)d_in[10];
    const float* be         = (const float*)d_in[11];
    const float* Wskip      = (const float*)d_in[12];
    const float* bskip      = (const float*)d_in[13];
    const float* Wbeta      = (const float*)d_in[14];
    const float* bn_gamma   = (const float*)d_in[15];
    const float* bn_beta    = (const float*)d_in[16];
    const float* Wout       = (const float*)d_in[17];
    const float* bout       = (const float*)d_in[18];
    const float* obias      = (const float*)d_in[19];
    float* out = (float*)d_out;

    char* ws = (char*)d_ws;
    size_t off = 0;
    auto alloc = [&](size_t bytes) -> void* {
        off = (off + 255) & ~(size_t)255;
        void* p = ws + off;
        off += bytes;
        return p;
    };
    const size_t NF = (size_t)NN * 128 * sizeof(float);
    float* xbuf    = (float*)alloc(NF);
    float* qb      = (float*)alloc(NF);
    float* xrb     = (float*)alloc(NF);
    unsigned int* kvb = (unsigned int*)alloc((size_t)NN * 64 * sizeof(unsigned int));
    _Float16* wt   = (_Float16*)alloc((size_t)12 * 16384 * sizeof(_Float16));
    int* row_ptr   = (int*)alloc((NN + 1) * sizeof(int));
    int* cnt       = (int*)alloc(NN * sizeof(int));
    int* esrc      = (int*)alloc(EE * sizeof(int));
    float* eat2    = (float*)alloc((size_t)EE * 2 * sizeof(float));
    float* bn_acc3 = (float*)alloc(3 * 256 * sizeof(float));
    float* gsum    = (float*)alloc(64 * sizeof(float));
    int* gcnt      = (int*)alloc(64 * sizeof(int));
    (void)ws_size; (void)n_in; (void)in_sizes; (void)out_size;

    // ---- CSR build (dst -> src, eattr reordered) + zero aux buffers + weight prep ----
    hipMemsetAsync(cnt, 0, NN * sizeof(int), stream);
    k_degprep<<<3125 + 768, 256, 0, stream>>>(eidx, cnt, Wq, Wk, Wv, Wskip, wt);
    k_scan<<<1, 1024, 0, stream>>>(cnt, row_ptr, bn_acc3, gsum, gcnt);
    k_scatter<<<(EE + 255) / 256, 256, 0, stream>>>(eidx, eattr, row_ptr, cnt, esrc, eat2);

    // ---- layers ----
    for (int l = 0; l < 3; ++l) {
        const float* Xl = (l == 0) ? x_in : xbuf;
        const float* prev_acc = (l == 0) ? bn_acc3 : bn_acc3 + (l - 1) * 256;
        k_gemm4<<<(NN + 63) / 64, 256, 0, stream>>>(
            Xl, wt + (size_t)l * 65536,
            bq + l * 128, bk + l * 128, bv + l * 128, bskip + l * 128,
            prev_acc, bn_gamma + (l == 0 ? 0 : (l - 1) * 128),
            bn_beta + (l == 0 ? 0 : (l - 1) * 128), (l == 0) ? 0 : 1,
            qb, kvb, xrb);
        k_attn<<<3125, 256, 0, stream>>>(
            qb, kvb, xrb, esrc, eat2, row_ptr,
            We + (size_t)l * 256, be + l * 128, Wbeta + (size_t)l * 384,
            xbuf, bn_acc3 + l * 256);
    }

    // ---- readout (BN affine+ELU of layer-2 fused in) ----
    k_pool<<<(NN + 15) / 16, 256, 0, stream>>>(xbuf, bn_acc3 + 2 * 256,
                                               bn_gamma + 2 * 128, bn_beta + 2 * 128,
                                               Wout, batch, gsum, gcnt);
    k_final<<<1, 64, 0, stream>>>(gsum, gcnt, bout, obias, out);
}